// Round 6
// baseline (379.692 us; speedup 1.0000x reference)
//
#include <hip/hip_runtime.h>
#include <math.h>

#define NDIR 5
#define E_ 16
#define W_ 3
#define D_ 128
#define P_ 256
#define B_ 4
#define ROWS 32
#define NPQ 8

typedef __attribute__((ext_vector_type(8))) short short8;
typedef __attribute__((ext_vector_type(4))) float f32x4;

struct RoutesArg { int r[E_][W_]; };

// Replicates Python _cantor_coord + stable argsort route construction on host.
static RoutesArg make_routes() {
    float coords[E_];
    for (int i = 0; i < E_; ++i) {
        double x = (double)i / (double)(E_ - 1);
        if (x < 1e-6) x = 1e-6;
        if (x > 1.0 - 1e-6) x = 1.0 - 1e-6;
        double val = 0.0, factor = 0.5;
        for (int d = 0; d < 8; ++d) {
            x *= 3.0;
            int digit = (int)x;
            x -= (double)digit;
            if (digit == 2) val += factor;
            factor *= 0.5;
        }
        coords[i] = (float)val;
    }
    RoutesArg R;
    for (int i = 0; i < E_; ++i) {
        float d[E_]; int idx[E_];
        for (int j = 0; j < E_; ++j) { d[j] = fabsf(coords[j] - coords[i]); idx[j] = j; }
        for (int a = 1; a < E_; ++a) {
            int key = idx[a]; float kd = d[key];
            int c = a - 1;
            while (c >= 0 && d[idx[c]] > kd) { idx[c + 1] = idx[c]; --c; }
            idx[c + 1] = key;
        }
        int top[W_] = { idx[0], idx[1], idx[2] };
        if (top[0] > top[1]) { int t = top[0]; top[0] = top[1]; top[1] = t; }
        if (top[1] > top[2]) { int t = top[1]; top[1] = top[2]; top[2] = t; }
        if (top[0] > top[1]) { int t = top[0]; top[0] = top[1]; top[1] = t; }
        for (int w = 0; w < W_; ++w) R.r[i][w] = top[w];
    }
    return R;
}

// HW packed f32->bf16 (RNE), T12 recipe. Pair order inside the dword is
// correctness-neutral here: A and B octets use the same permutation, which
// cancels in the MFMA dot product; den is computed pre-pack in fp32.
static __device__ __forceinline__ unsigned int cvt_pk_bf16(float lo, float hi) {
    unsigned int r;
    asm("v_cvt_pk_bf16_f32 %0, %1, %2" : "=v"(r) : "v"(lo), "v"(hi));
    return r;
}

static __device__ __forceinline__ short8 pack8(const float* a) {
    union { unsigned int u[4]; short8 s; } cv;
    cv.u[0] = cvt_pk_bf16(a[0], a[1]);
    cv.u[1] = cvt_pk_bf16(a[2], a[3]);
    cv.u[2] = cvt_pk_bf16(a[4], a[5]);
    cv.u[3] = cvt_pk_bf16(a[6], a[7]);
    return cv.s;
}

// Block = (e, b, pq-tile of 32 rows); 512 blocks, 4 waves.
// Waves split the k-range (6 of 24 k8-steps each) -> exps computed exactly
// once per block. x-loop inside: per-x tile scaled by fw[x]/den and
// accumulated into LDS redbuf via ds_add; one plain coalesced store at end.
__global__ __launch_bounds__(256) void cantor_fused_kernel(
    const float* __restrict__ Q, const float* __restrict__ K,
    const float* __restrict__ V, const float* __restrict__ betas,
    const float* __restrict__ temperature, const float* __restrict__ fusion,
    float* __restrict__ out, RoutesArg routes)
{
    __shared__ float s_lds[W_ * P_];        // 3 KB
    __shared__ float redbuf[ROWS * D_];     // 16 KB
    __shared__ float den_lds[4][2][16];     // 512 B

    // XCD-bijective swizzle: 512 = 8 XCDs x 64 (each XCD gets 2 e-values)
    const int orig = blockIdx.x;
    const int wg   = (orig & 7) * 64 + (orig >> 3);
    const int pq = wg & 7;
    const int b  = (wg >> 3) & 3;
    const int e  = wg >> 5;

    const int tid  = threadIdx.x;
    const int lane = tid & 63;
    const int wv   = tid >> 6;      // wave id -> k-range [wv*6, wv*6+6) k8-steps
    const int l15  = lane & 15;
    const int lg   = lane >> 4;

    const float temp = fabsf(temperature[0]) + 1e-6f;

    // fusion softmax (all 5 weights needed)
    float fw[NDIR];
    {
        float fmx = -1e30f, fsum = 0.f;
        #pragma unroll
        for (int i = 0; i < NDIR; ++i) { fw[i] = fusion[i]; fmx = fmaxf(fmx, fw[i]); }
        #pragma unroll
        for (int i = 0; i < NDIR; ++i) { fw[i] = __expf(fw[i] - fmx); fsum += fw[i]; }
        #pragma unroll
        for (int i = 0; i < NDIR; ++i) fw[i] /= fsum;
    }

    int rt[W_]; float bf3[W_];
    #pragma unroll
    for (int w = 0; w < W_; ++w) {
        rt[w] = routes.r[e][w];
        float bv = betas[e * E_ + rt[w]];
        bf3[w] = (rt[w] == e) ? 1.0f : 1.0f / (1.0f + __expf(-bv));
    }

    // zero the output accumulator tile
    #pragma unroll
    for (int i = tid; i < ROWS * D_; i += 256) redbuf[i] = 0.f;

    for (int x = 0; x < NDIR; ++x) {
        // ---- stage s = K * beta (768 floats) ----
        #pragma unroll
        for (int w = 0; w < W_; ++w)
            s_lds[w * P_ + tid] =
                K[(((size_t)(x * E_ + rt[w])) * B_ + b) * P_ + tid] * bf3[w];

        const float* Qb = Q + (((size_t)(x * E_ + e)) * B_ + b) * P_ + pq * ROWS;
        float q2[2];
        q2[0] = Qb[l15] / temp;
        q2[1] = Qb[16 + l15] / temp;

        __syncthreads();   // s_lds ready (also orders redbuf init / prev-x reads)

        f32x4 acc[2][8];
        #pragma unroll
        for (int fr = 0; fr < 2; ++fr)
            #pragma unroll
            for (int c = 0; c < 8; ++c)
                acc[fr][c] = (f32x4){0.f, 0.f, 0.f, 0.f};
        float den[2] = {0.f, 0.f};

        #pragma unroll 1
        for (int gi = 0; gi < 6; ++gi) {
            const int g  = wv * 6 + gi;     // global k8-step 0..23
            const int rw = g >> 3;          // route index
            const int k8 = g & 7;
            const int k0 = k8 * 32 + 8 * lg;

            // ---- issue all 64 B (V) loads early ----
            const float* __restrict__ vp =
                V + (((size_t)(x * E_ + rt[rw])) * B_ + b) * (size_t)(P_ * D_)
                  + (size_t)k0 * D_ + l15;
            float bv[8][8];
            #pragma unroll
            for (int c = 0; c < 8; ++c)
                #pragma unroll
                for (int i = 0; i < 8; ++i)
                    bv[c][i] = vp[i * D_ + c * 16];

            // ---- s octet (broadcast reads) ----
            float sv[8];
            {
                const float4 s0_ = *reinterpret_cast<const float4*>(&s_lds[rw * P_ + k0]);
                const float4 s1_ = *reinterpret_cast<const float4*>(&s_lds[rw * P_ + k0 + 4]);
                sv[0] = s0_.x; sv[1] = s0_.y; sv[2] = s0_.z; sv[3] = s0_.w;
                sv[4] = s1_.x; sv[5] = s1_.y; sv[6] = s1_.z; sv[7] = s1_.w;
            }

            // ---- A fragments: 16 exps (hides V load latency) ----
            short8 af[2];
            #pragma unroll
            for (int fr = 0; fr < 2; ++fr) {
                float ev[8];
                #pragma unroll
                for (int i = 0; i < 8; ++i) ev[i] = __expf(q2[fr] * sv[i]);
                den[fr] += ((ev[0] + ev[1]) + (ev[2] + ev[3])) +
                           ((ev[4] + ev[5]) + (ev[6] + ev[7]));
                af[fr] = pack8(ev);
            }

            // ---- pack B per column-group and MFMA immediately ----
            #pragma unroll
            for (int c = 0; c < 8; ++c) {
                const short8 bf8 = pack8(bv[c]);
                acc[0][c] = __builtin_amdgcn_mfma_f32_16x16x32_bf16(
                    af[0], bf8, acc[0][c], 0, 0, 0);
                acc[1][c] = __builtin_amdgcn_mfma_f32_16x16x32_bf16(
                    af[1], bf8, acc[1][c], 0, 0, 0);
            }
        }

        // ---- row denominators: reduce lg groups in-wave, waves via LDS ----
        #pragma unroll
        for (int fr = 0; fr < 2; ++fr) {
            den[fr] += __shfl_xor(den[fr], 16);
            den[fr] += __shfl_xor(den[fr], 32);
        }
        if (lane < 16) {
            den_lds[wv][0][l15] = den[0];
            den_lds[wv][1][l15] = den[1];
        }
        __syncthreads();   // den partials ready; all waves done with s_lds

        // ---- scale by fw[x]/den and accumulate into redbuf ----
        #pragma unroll
        for (int fr = 0; fr < 2; ++fr)
            #pragma unroll
            for (int r = 0; r < 4; ++r) {
                const int row16 = 4 * lg + r;   // C/D layout: row=4*(lane>>4)+reg
                const float dtot = den_lds[0][fr][row16] + den_lds[1][fr][row16]
                                 + den_lds[2][fr][row16] + den_lds[3][fr][row16];
                const float sc = fw[x] / dtot;
                const int rowbase = (fr * 16 + row16) * D_;
                #pragma unroll
                for (int c0 = 0; c0 < 8; ++c0) {
                    const int c = (c0 + lg) & 7;   // bank-stagger: 2-way max
                    atomicAdd(&redbuf[rowbase + c * 16 + l15], sc * acc[fr][c][r]);
                }
            }
        // next x's post-stage barrier orders these adds vs future reads
    }

    __syncthreads();   // all redbuf adds complete

    // ---- single coalesced store: out[b][e*256 + pq*32 + row][f] ----
    const size_t obase = ((size_t)b * (E_ * P_) + (size_t)e * P_ + pq * ROWS) * D_;
    const float4* rb = reinterpret_cast<const float4*>(redbuf);
    float4* ob = reinterpret_cast<float4*>(out + obase);
    #pragma unroll
    for (int seg = 0; seg < 4; ++seg)
        ob[seg * 256 + tid] = rb[seg * 256 + tid];
}

extern "C" void kernel_launch(void* const* d_in, const int* in_sizes, int n_in,
                              void* d_out, int out_size, void* d_ws, size_t ws_size,
                              hipStream_t stream) {
    (void)in_sizes; (void)n_in; (void)d_ws; (void)ws_size; (void)out_size;
    RoutesArg R = make_routes();
    const float* Q     = (const float*)d_in[0];
    const float* K     = (const float*)d_in[1];
    const float* V     = (const float*)d_in[2];
    const float* betas = (const float*)d_in[3];
    const float* tempr = (const float*)d_in[4];
    const float* fuse  = (const float*)d_in[5];
    float* out = (float*)d_out;

    dim3 grid(E_ * B_ * NPQ);   // 512 blocks
    dim3 block(256);
    hipLaunchKernelGGL(cantor_fused_kernel, grid, block, 0, stream,
                       Q, K, V, betas, tempr, fuse, out, R);
}

// Round 7
// 251.666 us; speedup vs baseline: 1.5087x; 1.5087x over previous
//
#include <hip/hip_runtime.h>
#include <math.h>

#define NDIR 5
#define E_ 16
#define W_ 3
#define D_ 128
#define P_ 256
#define B_ 4
#define ROWS 32
#define NPQ 8
#define RSTRIDE 132   // redbuf row stride (pad: 528 % 32 == 16 -> 2-way, free)

typedef __attribute__((ext_vector_type(8))) short short8;
typedef __attribute__((ext_vector_type(4))) float f32x4;
typedef __attribute__((ext_vector_type(8))) float f32x8;

struct RoutesArg { int r[E_][W_]; };

// Replicates Python _cantor_coord + stable argsort route construction on host.
static RoutesArg make_routes() {
    float coords[E_];
    for (int i = 0; i < E_; ++i) {
        double x = (double)i / (double)(E_ - 1);
        if (x < 1e-6) x = 1e-6;
        if (x > 1.0 - 1e-6) x = 1.0 - 1e-6;
        double val = 0.0, factor = 0.5;
        for (int d = 0; d < 8; ++d) {
            x *= 3.0;
            int digit = (int)x;
            x -= (double)digit;
            if (digit == 2) val += factor;
            factor *= 0.5;
        }
        coords[i] = (float)val;
    }
    RoutesArg R;
    for (int i = 0; i < E_; ++i) {
        float d[E_]; int idx[E_];
        for (int j = 0; j < E_; ++j) { d[j] = fabsf(coords[j] - coords[i]); idx[j] = j; }
        for (int a = 1; a < E_; ++a) {
            int key = idx[a]; float kd = d[key];
            int c = a - 1;
            while (c >= 0 && d[idx[c]] > kd) { idx[c + 1] = idx[c]; --c; }
            idx[c + 1] = key;
        }
        int top[W_] = { idx[0], idx[1], idx[2] };
        if (top[0] > top[1]) { int t = top[0]; top[0] = top[1]; top[1] = t; }
        if (top[1] > top[2]) { int t = top[1]; top[1] = top[2]; top[2] = t; }
        if (top[0] > top[1]) { int t = top[0]; top[0] = top[1]; top[1] = t; }
        for (int w = 0; w < W_; ++w) R.r[i][w] = top[w];
    }
    return R;
}

// HW packed f32->bf16 (RNE), proven correct in Round 6 (absmax 0.0039).
static __device__ __forceinline__ unsigned int cvt_pk_bf16(float lo, float hi) {
    unsigned int r;
    asm("v_cvt_pk_bf16_f32 %0, %1, %2" : "=v"(r) : "v"(lo), "v"(hi));
    return r;
}

// By-VALUE vector in, literal indices only -> stays in registers (rule #20).
static __device__ __forceinline__ short8 pack8(f32x8 a) {
    union { unsigned int u[4]; short8 s; } cv;
    cv.u[0] = cvt_pk_bf16(a[0], a[1]);
    cv.u[1] = cvt_pk_bf16(a[2], a[3]);
    cv.u[2] = cvt_pk_bf16(a[4], a[5]);
    cv.u[3] = cvt_pk_bf16(a[6], a[7]);
    return cv.s;
}

// Block = (e, b, pq-tile of 32 rows); 512 blocks, 4 waves.
// Waves split the k-range (6 of 24 k8-steps each) -> exps computed exactly
// once per block. x-loop inside: per-x tile scaled by fw[x]/den and
// accumulated into padded LDS redbuf via ds_add; one coalesced store at end.
__global__ __launch_bounds__(256, 1) void cantor_fused_kernel(
    const float* __restrict__ Q, const float* __restrict__ K,
    const float* __restrict__ V, const float* __restrict__ betas,
    const float* __restrict__ temperature, const float* __restrict__ fusion,
    float* __restrict__ out, RoutesArg routes)
{
    __shared__ float s_lds[W_ * P_];            // 3 KB
    __shared__ float redbuf[ROWS * RSTRIDE];    // 16.5 KB (padded rows)
    __shared__ float den_lds[4][2][16];         // 512 B

    // XCD-bijective swizzle: 512 = 8 XCDs x 64; the 8 pq-blocks sharing a
    // V-slice (same e,b) land on the same XCD's L2.
    const int orig = blockIdx.x;
    const int wg   = (orig & 7) * 64 + (orig >> 3);
    const int pq = wg & 7;
    const int b  = (wg >> 3) & 3;
    const int e  = wg >> 5;

    const int tid  = threadIdx.x;
    const int lane = tid & 63;
    const int wv   = tid >> 6;      // wave id -> k-range [wv*6, wv*6+6) k8-steps
    const int l15  = lane & 15;
    const int lg   = lane >> 4;

    const float temp = fabsf(temperature[0]) + 1e-6f;

    // fusion softmax (all 5 weights needed)
    float fw[NDIR];
    {
        float fmx = -1e30f, fsum = 0.f;
        #pragma unroll
        for (int i = 0; i < NDIR; ++i) { fw[i] = fusion[i]; fmx = fmaxf(fmx, fw[i]); }
        #pragma unroll
        for (int i = 0; i < NDIR; ++i) { fw[i] = __expf(fw[i] - fmx); fsum += fw[i]; }
        #pragma unroll
        for (int i = 0; i < NDIR; ++i) fw[i] /= fsum;
    }

    int rt[W_]; float bf3[W_];
    #pragma unroll
    for (int w = 0; w < W_; ++w) {
        rt[w] = routes.r[e][w];
        float bv_ = betas[e * E_ + rt[w]];
        bf3[w] = (rt[w] == e) ? 1.0f : 1.0f / (1.0f + __expf(-bv_));
    }

    // zero the output accumulator tile
    for (int i = tid; i < ROWS * RSTRIDE; i += 256) redbuf[i] = 0.f;

    for (int x = 0; x < NDIR; ++x) {
        // ---- stage s = K * beta (768 floats) ----
        #pragma unroll
        for (int w = 0; w < W_; ++w)
            s_lds[w * P_ + tid] =
                K[(((size_t)(x * E_ + rt[w])) * B_ + b) * P_ + tid] * bf3[w];

        const float* Qb = Q + (((size_t)(x * E_ + e)) * B_ + b) * P_ + pq * ROWS;
        float q2[2];
        q2[0] = Qb[l15] / temp;
        q2[1] = Qb[16 + l15] / temp;

        __syncthreads();   // s_lds ready (also orders redbuf init / prev-x adds)

        f32x4 acc[2][8];
        #pragma unroll
        for (int fr = 0; fr < 2; ++fr)
            #pragma unroll
            for (int c = 0; c < 8; ++c)
                acc[fr][c] = (f32x4){0.f, 0.f, 0.f, 0.f};
        float den[2] = {0.f, 0.f};

        #pragma unroll 1
        for (int gi = 0; gi < 6; ++gi) {
            const int g  = wv * 6 + gi;     // global k8-step 0..23
            const int rw = g >> 3;          // route index
            const int k8 = g & 7;
            const int k0 = k8 * 32 + 8 * lg;

            // ---- issue all 64 B (V) loads early; vector regs, literal idx ----
            const float* __restrict__ vp =
                V + (((size_t)(x * E_ + rt[rw])) * B_ + b) * (size_t)(P_ * D_)
                  + (size_t)k0 * D_ + l15;
            f32x8 bv[8];
            #pragma unroll
            for (int c = 0; c < 8; ++c)
                #pragma unroll
                for (int i = 0; i < 8; ++i)
                    bv[c][i] = vp[i * D_ + c * 16];

            // ---- s octet (broadcast reads) ----
            f32x8 sv;
            {
                const float4 s0_ = *reinterpret_cast<const float4*>(&s_lds[rw * P_ + k0]);
                const float4 s1_ = *reinterpret_cast<const float4*>(&s_lds[rw * P_ + k0 + 4]);
                sv[0] = s0_.x; sv[1] = s0_.y; sv[2] = s0_.z; sv[3] = s0_.w;
                sv[4] = s1_.x; sv[5] = s1_.y; sv[6] = s1_.z; sv[7] = s1_.w;
            }

            // ---- A fragments: 16 exps (hides V load latency) ----
            short8 af[2];
            #pragma unroll
            for (int fr = 0; fr < 2; ++fr) {
                f32x8 ev;
                #pragma unroll
                for (int i = 0; i < 8; ++i) ev[i] = __expf(q2[fr] * sv[i]);
                den[fr] += ((ev[0] + ev[1]) + (ev[2] + ev[3])) +
                           ((ev[4] + ev[5]) + (ev[6] + ev[7]));
                af[fr] = pack8(ev);
            }

            // ---- pack B per column-group and MFMA immediately ----
            #pragma unroll
            for (int c = 0; c < 8; ++c) {
                const short8 bf8 = pack8(bv[c]);
                acc[0][c] = __builtin_amdgcn_mfma_f32_16x16x32_bf16(
                    af[0], bf8, acc[0][c], 0, 0, 0);
                acc[1][c] = __builtin_amdgcn_mfma_f32_16x16x32_bf16(
                    af[1], bf8, acc[1][c], 0, 0, 0);
            }
        }

        // ---- row denominators: reduce lg groups in-wave, waves via LDS ----
        #pragma unroll
        for (int fr = 0; fr < 2; ++fr) {
            den[fr] += __shfl_xor(den[fr], 16);
            den[fr] += __shfl_xor(den[fr], 32);
        }
        if (lane < 16) {
            den_lds[wv][0][l15] = den[0];
            den_lds[wv][1][l15] = den[1];
        }
        __syncthreads();   // den partials ready; all waves done with s_lds

        // ---- scale by fw[x]/den and accumulate into redbuf (static idx) ----
        #pragma unroll
        for (int fr = 0; fr < 2; ++fr)
            #pragma unroll
            for (int r = 0; r < 4; ++r) {
                const int row16 = 4 * lg + r;   // C/D layout: row=4*(lane>>4)+reg
                const float dtot = den_lds[0][fr][row16] + den_lds[1][fr][row16]
                                 + den_lds[2][fr][row16] + den_lds[3][fr][row16];
                const float sc = fw[x] / dtot;
                const int rowbase = (fr * 16 + row16) * RSTRIDE;
                #pragma unroll
                for (int c = 0; c < 8; ++c)
                    atomicAdd(&redbuf[rowbase + c * 16 + l15], sc * acc[fr][c][r]);
            }
        // next x's post-stage barrier orders these adds vs future reads
    }

    __syncthreads();   // all redbuf adds complete

    // ---- coalesced store: out[b][e*256 + pq*32 + row][f] (unpad rows) ----
    const size_t obase = ((size_t)b * (E_ * P_) + (size_t)e * P_ + pq * ROWS) * D_;
    float4* ob = reinterpret_cast<float4*>(out + obase);
    #pragma unroll
    for (int t = tid; t < ROWS * 32; t += 256) {
        const int row = t >> 5;
        const int c4  = t & 31;
        ob[row * 32 + c4] =
            *reinterpret_cast<const float4*>(&redbuf[row * RSTRIDE + c4 * 4]);
    }
}

extern "C" void kernel_launch(void* const* d_in, const int* in_sizes, int n_in,
                              void* d_out, int out_size, void* d_ws, size_t ws_size,
                              hipStream_t stream) {
    (void)in_sizes; (void)n_in; (void)d_ws; (void)ws_size; (void)out_size;
    RoutesArg R = make_routes();
    const float* Q     = (const float*)d_in[0];
    const float* K     = (const float*)d_in[1];
    const float* V     = (const float*)d_in[2];
    const float* betas = (const float*)d_in[3];
    const float* tempr = (const float*)d_in[4];
    const float* fuse  = (const float*)d_in[5];
    float* out = (float*)d_out;

    dim3 grid(E_ * B_ * NPQ);   // 512 blocks
    dim3 block(256);
    hipLaunchKernelGGL(cantor_fused_kernel, grid, block, 0, stream,
                       Q, K, V, betas, tempr, fuse, out, R);
}

// Round 8
// 94.592 us; speedup vs baseline: 4.0140x; 2.6605x over previous
//
#include <hip/hip_runtime.h>
#include <math.h>

#define NDIR 5
#define E_ 16
#define W_ 3
#define D_ 128
#define P_ 256
#define B_ 4
#define ROWS 64
#define NPQ 4

typedef __attribute__((ext_vector_type(8))) short short8;
typedef __attribute__((ext_vector_type(4))) float f32x4;
typedef __attribute__((ext_vector_type(8))) float f32x8;

struct RoutesArg { int r[E_][W_]; };

// Replicates Python _cantor_coord + stable argsort route construction on host.
static RoutesArg make_routes() {
    float coords[E_];
    for (int i = 0; i < E_; ++i) {
        double x = (double)i / (double)(E_ - 1);
        if (x < 1e-6) x = 1e-6;
        if (x > 1.0 - 1e-6) x = 1.0 - 1e-6;
        double val = 0.0, factor = 0.5;
        for (int d = 0; d < 8; ++d) {
            x *= 3.0;
            int digit = (int)x;
            x -= (double)digit;
            if (digit == 2) val += factor;
            factor *= 0.5;
        }
        coords[i] = (float)val;
    }
    RoutesArg R;
    for (int i = 0; i < E_; ++i) {
        float d[E_]; int idx[E_];
        for (int j = 0; j < E_; ++j) { d[j] = fabsf(coords[j] - coords[i]); idx[j] = j; }
        for (int a = 1; a < E_; ++a) {
            int key = idx[a]; float kd = d[key];
            int c = a - 1;
            while (c >= 0 && d[idx[c]] > kd) { idx[c + 1] = idx[c]; --c; }
            idx[c + 1] = key;
        }
        int top[W_] = { idx[0], idx[1], idx[2] };
        if (top[0] > top[1]) { int t = top[0]; top[0] = top[1]; top[1] = t; }
        if (top[1] > top[2]) { int t = top[1]; top[1] = top[2]; top[2] = t; }
        if (top[0] > top[1]) { int t = top[0]; top[0] = top[1]; top[1] = t; }
        for (int w = 0; w < W_; ++w) R.r[i][w] = top[w];
    }
    return R;
}

// HW packed f32->bf16 (RNE), proven correct in Rounds 6/7 (absmax 0.0039).
static __device__ __forceinline__ unsigned int cvt_pk_bf16(float lo, float hi) {
    unsigned int r;
    asm("v_cvt_pk_bf16_f32 %0, %1, %2" : "=v"(r) : "v"(lo), "v"(hi));
    return r;
}

// By-VALUE vector in, literal indices only -> stays in registers (rule #20).
static __device__ __forceinline__ short8 pack8(f32x8 a) {
    union { unsigned int u[4]; short8 s; } cv;
    cv.u[0] = cvt_pk_bf16(a[0], a[1]);
    cv.u[1] = cvt_pk_bf16(a[2], a[3]);
    cv.u[2] = cvt_pk_bf16(a[4], a[5]);
    cv.u[3] = cvt_pk_bf16(a[6], a[7]);
    return cv.s;
}

// Block = (x, e, b, pq-tile of 64 rows); 1280 blocks, 4 waves.
// Waves split 2x2: (row-half of 32) x (f-half of 64). exp duplication x2
// (was x4 in R5), B-load duplication x2 (L1/L2-absorbed). No k-loop barriers.
// Each block emits its x's scaled contribution to a partial buffer.
template <bool ATOMIC>
__global__ __launch_bounds__(256) void cantor_partial_kernel(
    const float* __restrict__ Q, const float* __restrict__ K,
    const float* __restrict__ V, const float* __restrict__ betas,
    const float* __restrict__ temperature, const float* __restrict__ fusion,
    float* __restrict__ target, RoutesArg routes)
{
    __shared__ float s_lds[W_ * P_];   // 3 KB

    // XCD-bijective swizzle: 1280 blocks = 8 XCDs x 160
    const int orig = blockIdx.x;
    const int wg   = (orig & 7) * 160 + (orig >> 3);

    const int pq = wg & 3;
    const int b  = (wg >> 2) & 3;
    const int e  = (wg >> 4) & 15;
    const int x  = wg >> 8;

    const int tid  = threadIdx.x;
    const int lane = tid & 63;
    const int wv   = tid >> 6;
    const int l15  = lane & 15;
    const int lg   = lane >> 4;

    const int rowbase = (wv >> 1) * 32;   // wave's 32-row half
    const int f0      = (wv & 1) * 64;    // wave's 64-col half

    const float temp = fabsf(temperature[0]) + 1e-6f;

    // fusion softmax -> weight for this x
    float fwx;
    {
        float fv[NDIR], fmx = -1e30f, fsum = 0.f;
        #pragma unroll
        for (int i = 0; i < NDIR; ++i) { fv[i] = fusion[i]; fmx = fmaxf(fmx, fv[i]); }
        #pragma unroll
        for (int i = 0; i < NDIR; ++i) { fv[i] = __expf(fv[i] - fmx); fsum += fv[i]; }
        fwx = fv[x] / fsum;
    }

    int rt[W_]; float bf3[W_];
    #pragma unroll
    for (int w = 0; w < W_; ++w) {
        rt[w] = routes.r[e][w];
        float bv_ = betas[e * E_ + rt[w]];
        bf3[w] = (rt[w] == e) ? 1.0f : 1.0f / (1.0f + __expf(-bv_));
    }

    // stage s = K * beta (768 floats)
    #pragma unroll
    for (int w = 0; w < W_; ++w)
        s_lds[w * P_ + tid] =
            K[(((size_t)(x * E_ + rt[w])) * B_ + b) * P_ + tid] * bf3[w];

    // q rows this lane contributes to (A-fragment rows = l15 within 16-tile)
    const float* Qb = Q + (((size_t)(x * E_ + e)) * B_ + b) * P_ + pq * ROWS + rowbase;
    float q2[2];
    q2[0] = Qb[l15] / temp;
    q2[1] = Qb[16 + l15] / temp;

    __syncthreads();   // s_lds ready — the only barrier

    f32x4 acc[2][4];
    #pragma unroll
    for (int fr = 0; fr < 2; ++fr)
        #pragma unroll
        for (int c = 0; c < 4; ++c)
            acc[fr][c] = (f32x4){0.f, 0.f, 0.f, 0.f};
    float den[2] = {0.f, 0.f};

    #pragma unroll
    for (int w = 0; w < W_; ++w) {
        const float* __restrict__ Vw =
            V + (((size_t)(x * E_ + rt[w])) * B_ + b) * (size_t)(P_ * D_) + f0 + l15;
        const float* sb = s_lds + w * P_ + 8 * lg;
        for (int k8 = 0; k8 < 8; ++k8) {
            // ---- issue B (V) loads early (4 col-groups of the f-half) ----
            const float* vp = Vw + (size_t)(k8 * 32 + 8 * lg) * D_;
            f32x8 bv[4];
            #pragma unroll
            for (int c = 0; c < 4; ++c)
                #pragma unroll
                for (int i = 0; i < 8; ++i)
                    bv[c][i] = vp[i * D_ + c * 16];

            // ---- s octet for this lane group (broadcast reads) ----
            f32x8 sv;
            {
                const float4 s0_ = *reinterpret_cast<const float4*>(sb + k8 * 32);
                const float4 s1_ = *reinterpret_cast<const float4*>(sb + k8 * 32 + 4);
                sv[0] = s0_.x; sv[1] = s0_.y; sv[2] = s0_.z; sv[3] = s0_.w;
                sv[4] = s1_.x; sv[5] = s1_.y; sv[6] = s1_.z; sv[7] = s1_.w;
            }

            // ---- A fragments: 16 exps in registers (hides V latency) ----
            short8 af[2];
            #pragma unroll
            for (int fr = 0; fr < 2; ++fr) {
                f32x8 ev;
                #pragma unroll
                for (int i = 0; i < 8; ++i) ev[i] = __expf(q2[fr] * sv[i]);
                den[fr] += ((ev[0] + ev[1]) + (ev[2] + ev[3])) +
                           ((ev[4] + ev[5]) + (ev[6] + ev[7]));
                af[fr] = pack8(ev);
            }

            // ---- B fragments + 8 MFMAs ----
            #pragma unroll
            for (int c = 0; c < 4; ++c) {
                const short8 bf8 = pack8(bv[c]);
                acc[0][c] = __builtin_amdgcn_mfma_f32_16x16x32_bf16(
                    af[0], bf8, acc[0][c], 0, 0, 0);
                acc[1][c] = __builtin_amdgcn_mfma_f32_16x16x32_bf16(
                    af[1], bf8, acc[1][c], 0, 0, 0);
            }
        }
    }

    // ---- full-row denominators: sum across the 4 lane-groups ----
    #pragma unroll
    for (int fr = 0; fr < 2; ++fr) {
        den[fr] += __shfl_xor(den[fr], 16);
        den[fr] += __shfl_xor(den[fr], 32);
    }

    // ---- scale + write ----
    const size_t obase = ((((size_t)b * E_ + e) * NPQ) + pq) * (ROWS * D_);
    float* __restrict__ tgt = ATOMIC
        ? target
        : target + (size_t)x * ((size_t)B_ * E_ * NPQ * ROWS * D_);

    #pragma unroll
    for (int fr = 0; fr < 2; ++fr) {
        #pragma unroll
        for (int r = 0; r < 4; ++r) {
            const float dr = __shfl(den[fr], 4 * lg + r);   // den of row fr*16+4*lg+r
            const float sc = fwx / dr;
            const int row = rowbase + fr * 16 + 4 * lg + r;
            float* op = tgt + obase + (size_t)row * D_ + f0;
            #pragma unroll
            for (int c = 0; c < 4; ++c) {
                const float v = sc * acc[fr][c][r];
                if (ATOMIC) atomicAdd(op + c * 16 + l15, v);
                else        op[c * 16 + l15] = v;
            }
        }
    }
}

__global__ __launch_bounds__(256) void reduce5_kernel(
    const float* __restrict__ part, float* __restrict__ out)
{
    const size_t i = (size_t)blockIdx.x * 256 + threadIdx.x;   // float4 index
    const float4* __restrict__ p = reinterpret_cast<const float4*>(part);
    float4 a = p[i];
    #pragma unroll
    for (int x = 1; x < NDIR; ++x) {
        float4 t = p[(size_t)x * 524288 + i];
        a.x += t.x; a.y += t.y; a.z += t.z; a.w += t.w;
    }
    reinterpret_cast<float4*>(out)[i] = a;
}

extern "C" void kernel_launch(void* const* d_in, const int* in_sizes, int n_in,
                              void* d_out, int out_size, void* d_ws, size_t ws_size,
                              hipStream_t stream) {
    (void)in_sizes; (void)n_in;
    RoutesArg R = make_routes();
    const float* Q     = (const float*)d_in[0];
    const float* K     = (const float*)d_in[1];
    const float* V     = (const float*)d_in[2];
    const float* betas = (const float*)d_in[3];
    const float* tempr = (const float*)d_in[4];
    const float* fuse  = (const float*)d_in[5];
    float* out = (float*)d_out;

    const size_t partial_bytes = (size_t)NDIR * B_ * E_ * NPQ * ROWS * D_ * 4;  // ~42 MB
    dim3 grid(NDIR * E_ * B_ * NPQ);   // 1280
    dim3 block(256);

    if (ws_size >= partial_bytes) {
        float* part = (float*)d_ws;
        hipLaunchKernelGGL((cantor_partial_kernel<false>), grid, block, 0, stream,
                           Q, K, V, betas, tempr, fuse, part, R);
        hipLaunchKernelGGL(reduce5_kernel, dim3(2048), block, 0, stream,
                           part, out);
    } else {
        (void)hipMemsetAsync(d_out, 0, (size_t)out_size * 4, stream);
        hipLaunchKernelGGL((cantor_partial_kernel<true>), grid, block, 0, stream,
                           Q, K, V, betas, tempr, fuse, out, R);
    }
}

// Round 9
// 93.661 us; speedup vs baseline: 4.0539x; 1.0099x over previous
//
#include <hip/hip_runtime.h>
#include <math.h>

#define NDIR 5
#define E_ 16
#define W_ 3
#define D_ 128
#define P_ 256
#define B_ 4
#define ROWS 64
#define NPQ 4

typedef __attribute__((ext_vector_type(8))) short short8;
typedef __attribute__((ext_vector_type(4))) float f32x4;
typedef __attribute__((ext_vector_type(8))) float f32x8;

struct RoutesArg { int r[E_][W_]; };

// Replicates Python _cantor_coord + stable argsort route construction on host.
static RoutesArg make_routes() {
    float coords[E_];
    for (int i = 0; i < E_; ++i) {
        double x = (double)i / (double)(E_ - 1);
        if (x < 1e-6) x = 1e-6;
        if (x > 1.0 - 1e-6) x = 1.0 - 1e-6;
        double val = 0.0, factor = 0.5;
        for (int d = 0; d < 8; ++d) {
            x *= 3.0;
            int digit = (int)x;
            x -= (double)digit;
            if (digit == 2) val += factor;
            factor *= 0.5;
        }
        coords[i] = (float)val;
    }
    RoutesArg R;
    for (int i = 0; i < E_; ++i) {
        float d[E_]; int idx[E_];
        for (int j = 0; j < E_; ++j) { d[j] = fabsf(coords[j] - coords[i]); idx[j] = j; }
        for (int a = 1; a < E_; ++a) {
            int key = idx[a]; float kd = d[key];
            int c = a - 1;
            while (c >= 0 && d[idx[c]] > kd) { idx[c + 1] = idx[c]; --c; }
            idx[c + 1] = key;
        }
        int top[W_] = { idx[0], idx[1], idx[2] };
        if (top[0] > top[1]) { int t = top[0]; top[0] = top[1]; top[1] = t; }
        if (top[1] > top[2]) { int t = top[1]; top[1] = top[2]; top[2] = t; }
        if (top[0] > top[1]) { int t = top[0]; top[0] = top[1]; top[1] = t; }
        for (int w = 0; w < W_; ++w) R.r[i][w] = top[w];
    }
    return R;
}

// HW packed f32->bf16 (RNE), proven correct in Rounds 6/7 (absmax 0.0039).
static __device__ __forceinline__ unsigned int cvt_pk_bf16(float lo, float hi) {
    unsigned int r;
    asm("v_cvt_pk_bf16_f32 %0, %1, %2" : "=v"(r) : "v"(lo), "v"(hi));
    return r;
}

// By-VALUE vector in, literal indices only -> stays in registers (rule #20).
static __device__ __forceinline__ short8 pack8(f32x8 a) {
    union { unsigned int u[4]; short8 s; } cv;
    cv.u[0] = cvt_pk_bf16(a[0], a[1]);
    cv.u[1] = cvt_pk_bf16(a[2], a[3]);
    cv.u[2] = cvt_pk_bf16(a[4], a[5]);
    cv.u[3] = cvt_pk_bf16(a[6], a[7]);
    return cv.s;
}

// Block = (x, e, b, pq-tile of 64 rows); 1280 blocks, 4 waves.
// Waves split 2x2: (row-half of 32) x (f-half of 64). exp duplication x2
// (was x4 in R5), B-load duplication x2 (L1/L2-absorbed). No k-loop barriers.
// Each block emits its x's scaled contribution to a partial buffer.
template <bool ATOMIC>
__global__ __launch_bounds__(256) void cantor_partial_kernel(
    const float* __restrict__ Q, const float* __restrict__ K,
    const float* __restrict__ V, const float* __restrict__ betas,
    const float* __restrict__ temperature, const float* __restrict__ fusion,
    float* __restrict__ target, RoutesArg routes)
{
    __shared__ float s_lds[W_ * P_];   // 3 KB

    // XCD-bijective swizzle: 1280 blocks = 8 XCDs x 160
    const int orig = blockIdx.x;
    const int wg   = (orig & 7) * 160 + (orig >> 3);

    const int pq = wg & 3;
    const int b  = (wg >> 2) & 3;
    const int e  = (wg >> 4) & 15;
    const int x  = wg >> 8;

    const int tid  = threadIdx.x;
    const int lane = tid & 63;
    const int wv   = tid >> 6;
    const int l15  = lane & 15;
    const int lg   = lane >> 4;

    const int rowbase = (wv >> 1) * 32;   // wave's 32-row half
    const int f0      = (wv & 1) * 64;    // wave's 64-col half

    const float temp = fabsf(temperature[0]) + 1e-6f;

    // fusion softmax -> weight for this x
    float fwx;
    {
        float fv[NDIR], fmx = -1e30f, fsum = 0.f;
        #pragma unroll
        for (int i = 0; i < NDIR; ++i) { fv[i] = fusion[i]; fmx = fmaxf(fmx, fv[i]); }
        #pragma unroll
        for (int i = 0; i < NDIR; ++i) { fv[i] = __expf(fv[i] - fmx); fsum += fv[i]; }
        fwx = fv[x] / fsum;
    }

    int rt[W_]; float bf3[W_];
    #pragma unroll
    for (int w = 0; w < W_; ++w) {
        rt[w] = routes.r[e][w];
        float bv_ = betas[e * E_ + rt[w]];
        bf3[w] = (rt[w] == e) ? 1.0f : 1.0f / (1.0f + __expf(-bv_));
    }

    // stage s = K * beta (768 floats)
    #pragma unroll
    for (int w = 0; w < W_; ++w)
        s_lds[w * P_ + tid] =
            K[(((size_t)(x * E_ + rt[w])) * B_ + b) * P_ + tid] * bf3[w];

    // q rows this lane contributes to (A-fragment rows = l15 within 16-tile)
    const float* Qb = Q + (((size_t)(x * E_ + e)) * B_ + b) * P_ + pq * ROWS + rowbase;
    float q2[2];
    q2[0] = Qb[l15] / temp;
    q2[1] = Qb[16 + l15] / temp;

    __syncthreads();   // s_lds ready — the only barrier

    f32x4 acc[2][4];
    #pragma unroll
    for (int fr = 0; fr < 2; ++fr)
        #pragma unroll
        for (int c = 0; c < 4; ++c)
            acc[fr][c] = (f32x4){0.f, 0.f, 0.f, 0.f};
    float den[2] = {0.f, 0.f};

    #pragma unroll
    for (int w = 0; w < W_; ++w) {
        const float* __restrict__ Vw =
            V + (((size_t)(x * E_ + rt[w])) * B_ + b) * (size_t)(P_ * D_) + f0 + l15;
        const float* sb = s_lds + w * P_ + 8 * lg;
        for (int k8 = 0; k8 < 8; ++k8) {
            // ---- issue B (V) loads early (4 col-groups of the f-half) ----
            const float* vp = Vw + (size_t)(k8 * 32 + 8 * lg) * D_;
            f32x8 bv[4];
            #pragma unroll
            for (int c = 0; c < 4; ++c)
                #pragma unroll
                for (int i = 0; i < 8; ++i)
                    bv[c][i] = vp[i * D_ + c * 16];

            // ---- s octet for this lane group (broadcast reads) ----
            f32x8 sv;
            {
                const float4 s0_ = *reinterpret_cast<const float4*>(sb + k8 * 32);
                const float4 s1_ = *reinterpret_cast<const float4*>(sb + k8 * 32 + 4);
                sv[0] = s0_.x; sv[1] = s0_.y; sv[2] = s0_.z; sv[3] = s0_.w;
                sv[4] = s1_.x; sv[5] = s1_.y; sv[6] = s1_.z; sv[7] = s1_.w;
            }

            // ---- A fragments: 16 exps in registers (hides V latency) ----
            short8 af[2];
            #pragma unroll
            for (int fr = 0; fr < 2; ++fr) {
                f32x8 ev;
                #pragma unroll
                for (int i = 0; i < 8; ++i) ev[i] = __expf(q2[fr] * sv[i]);
                den[fr] += ((ev[0] + ev[1]) + (ev[2] + ev[3])) +
                           ((ev[4] + ev[5]) + (ev[6] + ev[7]));
                af[fr] = pack8(ev);
            }

            // ---- B fragments + 8 MFMAs ----
            #pragma unroll
            for (int c = 0; c < 4; ++c) {
                const short8 bf8 = pack8(bv[c]);
                acc[0][c] = __builtin_amdgcn_mfma_f32_16x16x32_bf16(
                    af[0], bf8, acc[0][c], 0, 0, 0);
                acc[1][c] = __builtin_amdgcn_mfma_f32_16x16x32_bf16(
                    af[1], bf8, acc[1][c], 0, 0, 0);
            }
        }
    }

    // ---- full-row denominators: sum across the 4 lane-groups ----
    #pragma unroll
    for (int fr = 0; fr < 2; ++fr) {
        den[fr] += __shfl_xor(den[fr], 16);
        den[fr] += __shfl_xor(den[fr], 32);
    }

    // ---- scale + write ----
    const size_t obase = ((((size_t)b * E_ + e) * NPQ) + pq) * (ROWS * D_);
    float* __restrict__ tgt = ATOMIC
        ? target
        : target + (size_t)x * ((size_t)B_ * E_ * NPQ * ROWS * D_);

    #pragma unroll
    for (int fr = 0; fr < 2; ++fr) {
        #pragma unroll
        for (int r = 0; r < 4; ++r) {
            const float dr = __shfl(den[fr], 4 * lg + r);   // den of row fr*16+4*lg+r
            const float sc = fwx / dr;
            const int row = rowbase + fr * 16 + 4 * lg + r;
            float* op = tgt + obase + (size_t)row * D_ + f0;
            #pragma unroll
            for (int c = 0; c < 4; ++c) {
                const float v = sc * acc[fr][c][r];
                if (ATOMIC) atomicAdd(op + c * 16 + l15, v);
                else        op[c * 16 + l15] = v;
            }
        }
    }
}

__global__ __launch_bounds__(256) void reduce5_kernel(
    const float* __restrict__ part, float* __restrict__ out)
{
    const size_t i = (size_t)blockIdx.x * 256 + threadIdx.x;   // float4 index
    const float4* __restrict__ p = reinterpret_cast<const float4*>(part);
    float4 a = p[i];
    #pragma unroll
    for (int x = 1; x < NDIR; ++x) {
        float4 t = p[(size_t)x * 524288 + i];
        a.x += t.x; a.y += t.y; a.z += t.z; a.w += t.w;
    }
    reinterpret_cast<float4*>(out)[i] = a;
}

extern "C" void kernel_launch(void* const* d_in, const int* in_sizes, int n_in,
                              void* d_out, int out_size, void* d_ws, size_t ws_size,
                              hipStream_t stream) {
    (void)in_sizes; (void)n_in;
    RoutesArg R = make_routes();
    const float* Q     = (const float*)d_in[0];
    const float* K     = (const float*)d_in[1];
    const float* V     = (const float*)d_in[2];
    const float* betas = (const float*)d_in[3];
    const float* tempr = (const float*)d_in[4];
    const float* fuse  = (const float*)d_in[5];
    float* out = (float*)d_out;

    const size_t partial_bytes = (size_t)NDIR * B_ * E_ * NPQ * ROWS * D_ * 4;  // ~42 MB
    dim3 grid(NDIR * E_ * B_ * NPQ);   // 1280
    dim3 block(256);

    if (ws_size >= partial_bytes) {
        float* part = (float*)d_ws;
        hipLaunchKernelGGL((cantor_partial_kernel<false>), grid, block, 0, stream,
                           Q, K, V, betas, tempr, fuse, part, R);
        hipLaunchKernelGGL(reduce5_kernel, dim3(2048), block, 0, stream,
                           part, out);
    } else {
        (void)hipMemsetAsync(d_out, 0, (size_t)out_size * 4, stream);
        hipLaunchKernelGGL((cantor_partial_kernel<true>), grid, block, 0, stream,
                           Q, K, V, betas, tempr, fuse, out, R);
    }
}